// Round 12
// baseline (176.326 us; speedup 1.0000x reference)
//
#include <hip/hip_runtime.h>

typedef __attribute__((ext_vector_type(8))) short short8;
typedef __attribute__((ext_vector_type(16))) float f32x16;
typedef __attribute__((ext_vector_type(4))) unsigned short ushort4v;

#define BN_EPS 1e-5f
#define KOFF 27

static __device__ __forceinline__ unsigned short f2bf(float f) {
  unsigned int u = __float_as_uint(f);
  u += 0x7fffu + ((u >> 16) & 1u);
  return (unsigned short)(u >> 16);
}

static __device__ __forceinline__ float silu_f(float z) {
  return z / (1.f + __expf(-z));
}

// ---- fused prep: [0,864) pack W1+W2, [864,872) time MLP, [872,...) bn1+silu
// pack: W[k, ci, co] (f32) -> bf16 MFMA B-fragment order (32x32x16).
// Fragment f = k*8 + ks*2 + cb : lane l elem j <- W[k][ks*16 + (l>>5)*8 + j][cb*32 + (l&31)]
__global__ void prep_all(const float* __restrict__ t, const float* __restrict__ Wt,
                         const float* __restrict__ bt,
                         float* __restrict__ scale_eff, float* __restrict__ shift,
                         const float* __restrict__ W1, const float* __restrict__ W2,
                         unsigned short* __restrict__ Wp1, unsigned short* __restrict__ Wp2,
                         const float* __restrict__ x, const float* __restrict__ g1,
                         const float* __restrict__ b1, const float* __restrict__ m1,
                         const float* __restrict__ v1, unsigned short* __restrict__ a1bf,
                         int total) {
  const int bid = blockIdx.x;
  if (bid < 864) {
    int tid = bid * 256 + threadIdx.x;          // 0 .. 221183 = 2*tot
    const int tot = KOFF * 4 * 2 * 64 * 8;
    const float* W = W1;
    unsigned short* Wp = Wp1;
    if (tid >= tot) { tid -= tot; W = W2; Wp = Wp2; }
    int j = tid & 7, lane = (tid >> 3) & 63, cbb = (tid >> 9) & 1,
        ks = (tid >> 10) & 3, k = tid >> 12;
    int ci = ks * 16 + (lane >> 5) * 8 + j;
    int co = cbb * 32 + (lane & 31);
    Wp[tid] = f2bf(W[(k * 64 + ci) * 64 + co]);
  } else if (bid < 872) {
    int tid = (bid - 864) * 256 + threadIdx.x;  // 0..2047 = 16 batches * 128 out
    int bi = tid >> 7, co = tid & 127;
    float acc = bt[co];
    for (int e = 0; e < 256; ++e) {
      float tv = t[bi * 256 + e];
      acc += silu_f(tv) * Wt[e * 128 + co];
    }
    if (co < 64) scale_eff[bi * 64 + co] = 1.f + acc;
    else         shift[bi * 64 + (co - 64)] = acc;
  } else {
    int i = ((bid - 872) * 256 + threadIdx.x) * 4;
    if (i >= total) {
      if (i < total + 64) *(ushort4v*)(a1bf + i) = (ushort4v){0, 0, 0, 0};
      return;
    }
    float4 v = *(const float4*)(x + i);
    int c = i & 63;
    float4 g = *(const float4*)(g1 + c);
    float4 b = *(const float4*)(b1 + c);
    float4 m = *(const float4*)(m1 + c);
    float4 vv = *(const float4*)(v1 + c);
    ushort4v r;
    float sx = g.x * rsqrtf(vv.x + BN_EPS);
    float sy = g.y * rsqrtf(vv.y + BN_EPS);
    float sz = g.z * rsqrtf(vv.z + BN_EPS);
    float sw = g.w * rsqrtf(vv.w + BN_EPS);
    r.x = f2bf(silu_f((v.x - m.x) * sx + b.x));
    r.y = f2bf(silu_f((v.y - m.y) * sy + b.y));
    r.z = f2bf(silu_f((v.z - m.z) * sz + b.z));
    r.w = f2bf(silu_f((v.w - m.w) * sw + b.w));
    *(ushort4v*)(a1bf + i) = r;
  }
}

// ---- sparse conv: WAVE-PRIVATE pipeline, ZERO barriers.
// Block = 256 threads / 4 independent waves / 128 nodes. Wave w owns rows
// n0 + w*32 .. +31 and ALL 64 cols (acc0 cols 0-31, acc1 cols 32-63).
// Each wave gathers its own 32 rows (4 KB/tap) into its own 8 KB LDS dbuf;
// producer == consumer wave -> plain C++ LDS ordering, compiler-inserted lgkmcnt,
// NO s_barrier anywhere. Depth-3 gather (st slot = tap%3), W dbuf (8 frags,
// parity), rv slot = tap&1, LDS buf = tap&1.
// Iter k: DSWRITE(k+1) ; GLOAD(k+3) ; LDVG(k+4) ; WLOAD(k+1) ; COMPUTE(k).
// Write-side XOR swizzle: phys chunk = q0 ^ (row&7); read p = (ks*2+half)^(r32&7).
// MODE 0: epilogue = +bias, FiLM, bn2+silu -> bf16 a2 (block 0 zeroes a2 row N)
// MODE 1: epilogue = +bias + residual x -> f32 out
template <int MODE>
__global__ __launch_bounds__(256, 3) void conv_k(
    const unsigned short* __restrict__ act, const int* __restrict__ idx,
    const int* __restrict__ valid, const unsigned short* __restrict__ Wp,
    const float* __restrict__ bias,
    const float* __restrict__ scale_eff, const float* __restrict__ shift,
    const int* __restrict__ bidx,
    const float* __restrict__ g2, const float* __restrict__ b2,
    const float* __restrict__ m2, const float* __restrict__ v2,
    const float* __restrict__ xres,
    unsigned short* __restrict__ out_bf, float* __restrict__ out_f, int N) {
  __shared__ unsigned short lds[4][2][32 * 64];   // [wave][dbuf][rows x cols]

  if (MODE == 0 && blockIdx.x == 0 && threadIdx.x < 64) {
    out_bf[(size_t)N * 64 + threadIdx.x] = 0;  // zero row for conv2's invalid taps
  }
  const int tid = threadIdx.x;
  const int lane = tid & 63;
  const int wid = tid >> 6;
  const int half = lane >> 5;   // 0/1
  const int r32 = lane & 31;
  const int n0 = blockIdx.x * 128;

  const int q0 = lane & 7;      // chunk this lane stages
  const int sg = lane >> 3;     // row-subgroup 0..7
  const int nLV = min(n0 + wid * 32 + r32, N - 1);  // node this lane tracks rows for

  f32x16 acc0, acc1;
#pragma unroll
  for (int i = 0; i < 16; ++i) { acc0[i] = 0.f; acc1[i] = 0.f; }

  int rvA, rvB;                     // per-lane gather row, slot = tap&1
  short8 st0[4], st1[4], st2[4];    // staged chunks, slot = tap%3 (4 x 16B each)
  short8 wrA[8], wrB[8];            // W fragments (ks*2+cb), parity = tap&1

#define LDVG(kk) \
    (valid[(size_t)(kk) * N + nLV] ? idx[(size_t)(kk) * N + nLV] : N)

  // staging: instr i covers local rows i*8 + sg (sg=0..7), chunk q0
#define GLOAD(st, rv) do { \
    _Pragma("unroll") \
    for (int i = 0; i < 4; ++i) { \
      int rg = __shfl(rv, i * 8 + sg); \
      st[i] = *(const short8*)(act + (size_t)rg * 64 + q0 * 8); \
    } } while (0)

  // phys chunk = q0 ^ (row&7) = q0 ^ sg
#define DSWRITE(buf, st) do { \
    _Pragma("unroll") \
    for (int i = 0; i < 4; ++i) \
      *(short8*)(&lds[wid][buf][(i * 8 + sg) * 64 + (q0 ^ sg) * 8]) = st[i]; \
  } while (0)

#define WLOAD(kk, wr) do { \
    _Pragma("unroll") \
    for (int f = 0; f < 8; ++f) \
      wr[f] = ((const short8*)Wp)[((size_t)(kk) * 8 + f) * 64 + lane]; \
  } while (0)

  // read phys p = (ks*2 + half) ^ (row&7); row == r32
#define COMPUTE(buf, wr) do { \
    _Pragma("unroll") \
    for (int ks = 0; ks < 4; ++ks) { \
      int p = (ks * 2 + half) ^ (r32 & 7); \
      short8 av = *(const short8*)(&lds[wid][buf][r32 * 64 + p * 8]); \
      acc0 = __builtin_amdgcn_mfma_f32_32x32x16_bf16(av, wr[ks * 2 + 0], acc0, 0, 0, 0); \
      acc1 = __builtin_amdgcn_mfma_f32_32x32x16_bf16(av, wr[ks * 2 + 1], acc1, 0, 0, 0); \
    } } while (0)

  // prologue: gather taps 0,1,2; rows(3) -> rvB; W(0); write tap 0
  {
    int tt = LDVG(0);
    GLOAD(st0, tt);
    tt = LDVG(1);
    GLOAD(st1, tt);
    tt = LDVG(2);
    GLOAD(st2, tt);
  }
  rvB = LDVG(3);
  rvA = 0;
  WLOAD(0, wrA);
  DSWRITE(0, st0);

#pragma unroll
  for (int k = 0; k < KOFF; ++k) {
    if (k + 1 < KOFF) {            // tap k+1 lives in st[(k+1)%3]
      const int s = (k + 1) % 3;
      if (s == 0)      DSWRITE((k + 1) & 1, st0);
      else if (s == 1) DSWRITE((k + 1) & 1, st1);
      else             DSWRITE((k + 1) & 1, st2);
    }
    if (k + 3 < KOFF) {            // gather tap k+3 -> st[(k+3)%3], rows in rv[(k+1)&1]
      const int s = (k + 3) % 3;
      if ((k + 1) & 1) {
        if (s == 0) GLOAD(st0, rvB); else if (s == 1) GLOAD(st1, rvB); else GLOAD(st2, rvB);
      } else {
        if (s == 0) GLOAD(st0, rvA); else if (s == 1) GLOAD(st1, rvA); else GLOAD(st2, rvA);
      }
    }
    if (k + 4 < KOFF) {            // rows(k+4) -> rv[k&1]
      if (k & 1) rvB = LDVG(k + 4); else rvA = LDVG(k + 4);
    }
    if (k + 1 < KOFF) {
      if ((k + 1) & 1) WLOAD(k + 1, wrB); else WLOAD(k + 1, wrA);
    }
    if (k & 1) COMPUTE(1, wrB); else COMPUTE(0, wrA);
  }
#undef LDVG
#undef GLOAD
#undef DSWRITE
#undef WLOAD
#undef COMPUTE

  // D frag: col = cb*32 + r32, row = wid*32 + (r&3) + 8*(r>>2) + 4*half
  if (MODE == 0) {
#pragma unroll
    for (int cb = 0; cb < 2; ++cb) {
      f32x16 a = cb ? acc1 : acc0;
      const int c = cb * 32 + r32;
      float bb = bias[c];
      float s2v = g2[c] * rsqrtf(v2[c] + BN_EPS);
      float o2v = b2[c] - m2[c] * s2v;
#pragma unroll
      for (int r = 0; r < 16; ++r) {
        int rowD = (r & 3) + 8 * (r >> 2) + 4 * half;
        int n = n0 + wid * 32 + rowD;
        if (n < N) {
          int bi = bidx[n];
          float h = a[r] + bb;
          h = scale_eff[bi * 64 + c] * h + shift[bi * 64 + c];
          float z = h * s2v + o2v;
          out_bf[(size_t)n * 64 + c] = f2bf(silu_f(z));
        }
      }
    }
  } else {
#pragma unroll
    for (int cb = 0; cb < 2; ++cb) {
      f32x16 a = cb ? acc1 : acc0;
      const int c = cb * 32 + r32;
      float bb = bias[c];
#pragma unroll
      for (int r = 0; r < 16; ++r) {
        int rowD = (r & 3) + 8 * (r >> 2) + 4 * half;
        int n = n0 + wid * 32 + rowD;
        if (n < N) {
          out_f[(size_t)n * 64 + c] = a[r] + bb + xres[(size_t)n * 64 + c];
        }
      }
    }
  }
}

extern "C" void kernel_launch(void* const* d_in, const int* in_sizes, int n_in,
                              void* d_out, int out_size, void* d_ws, size_t ws_size,
                              hipStream_t stream) {
  const float* x    = (const float*)d_in[0];
  const float* t    = (const float*)d_in[1];
  const int*   b    = (const int*)d_in[2];
  const int*   kidx = (const int*)d_in[3];
  const int*   kval = (const int*)d_in[4];
  const float* bn1g = (const float*)d_in[5];
  const float* bn1b = (const float*)d_in[6];
  const float* bn1m = (const float*)d_in[7];
  const float* bn1v = (const float*)d_in[8];
  const float* W1   = (const float*)d_in[9];
  const float* b1c  = (const float*)d_in[10];
  const float* bn2g = (const float*)d_in[11];
  const float* bn2b = (const float*)d_in[12];
  const float* bn2m = (const float*)d_in[13];
  const float* bn2v = (const float*)d_in[14];
  const float* W2   = (const float*)d_in[15];
  const float* b2c  = (const float*)d_in[16];
  const float* Wt   = (const float*)d_in[17];
  const float* bt   = (const float*)d_in[18];
  float* out = (float*)d_out;

  const int N = in_sizes[2];        // 100000
  const int total = N * 64;

  // workspace layout (bytes); act buffers have N+1 rows (row N = zeros)
  char* ws = (char*)d_ws;
  size_t actB = ((size_t)(N + 1) * 64 * 2 + 255) & ~(size_t)255;
  unsigned short* a1bf = (unsigned short*)ws;
  unsigned short* a2bf = (unsigned short*)(ws + actB);
  const size_t wpackB = (size_t)KOFF * 4 * 2 * 64 * 8 * 2;  // 221184 B
  unsigned short* W1p = (unsigned short*)(ws + 2 * actB);
  unsigned short* W2p = (unsigned short*)(ws + 2 * actB + wpackB);
  float* scale_eff = (float*)(ws + 2 * actB + 2 * wpackB);
  float* shiftp    = scale_eff + 16 * 64;

  int bnblk = (total / 4 + 16 + 255) / 256;
  prep_all<<<872 + bnblk, 256, 0, stream>>>(t, Wt, bt, scale_eff, shiftp,
                                            W1, W2, W1p, W2p,
                                            x, bn1g, bn1b, bn1m, bn1v, a1bf, total);

  int nblk = (N + 127) / 128;
  conv_k<0><<<nblk, 256, 0, stream>>>(a1bf, kidx, kval, W1p, b1c, scale_eff,
                                      shiftp, b, bn2g, bn2b, bn2m, bn2v,
                                      nullptr, a2bf, nullptr, N);
  conv_k<1><<<nblk, 256, 0, stream>>>(a2bf, kidx, kval, W2p, b2c, nullptr, nullptr,
                                      nullptr, nullptr, nullptr, nullptr, nullptr,
                                      x, nullptr, out, N);
}

// Round 13
// 127.465 us; speedup vs baseline: 1.3833x; 1.3833x over previous
//
#include <hip/hip_runtime.h>

typedef __attribute__((ext_vector_type(16))) float f32x16;
typedef __attribute__((ext_vector_type(2))) long lv2;
typedef __attribute__((ext_vector_type(2))) unsigned int uint2v;

#define BN_EPS 1e-5f
#define KOFF 27
#define LSTRIDE 72   // LDS row stride in bytes (64B row + 8B pad -> <=4-way bank alias)

static __device__ __forceinline__ float silu_f(float z) {
  return z / (1.f + __expf(-z));
}

// f32 -> fp8 e4m3 (OCP on gfx950), RNE+sat via HW cvt
static __device__ __forceinline__ unsigned char f2fp8(float v) {
  unsigned int p = (unsigned int)__builtin_amdgcn_cvt_pk_fp8_f32(v, 0.f, 0, 0);
  return (unsigned char)(p & 0xffu);
}

// ---- fused prep:
// [0,864)        : pack W1+W2 -> fp8 MFMA B-frag order (32x32x16, K=16)
//                  frag f=ks*2+cb: lane l byte j <- W[k][ks*16+(l>>5)*8+j][cb*32+(l&31)]
// [864,872)      : time MLP (f32)
// [872, ...)     : a1 = fp8(silu(bn1(x))), 8 elems/thread; zero row N
__global__ void prep_all(const float* __restrict__ t, const float* __restrict__ Wt,
                         const float* __restrict__ bt,
                         float* __restrict__ scale_eff, float* __restrict__ shift,
                         const float* __restrict__ W1, const float* __restrict__ W2,
                         unsigned char* __restrict__ Wp1, unsigned char* __restrict__ Wp2,
                         const float* __restrict__ x, const float* __restrict__ g1,
                         const float* __restrict__ b1, const float* __restrict__ m1,
                         const float* __restrict__ v1, unsigned char* __restrict__ a1,
                         int total) {
  const int bid = blockIdx.x;
  if (bid < 864) {
    int tid = bid * 256 + threadIdx.x;          // 0 .. 221183 = 2*tot
    const int tot = KOFF * 8 * 64 * 8;          // 110592 bytes per W
    const float* W = W1;
    unsigned char* Wp = Wp1;
    if (tid >= tot) { tid -= tot; W = W2; Wp = Wp2; }
    int j = tid & 7, lane = (tid >> 3) & 63, f = (tid >> 9) & 7, k = tid >> 12;
    int ci = (f >> 1) * 16 + (lane >> 5) * 8 + j;
    int co = (f & 1) * 32 + (lane & 31);
    Wp[tid] = f2fp8(W[(k * 64 + ci) * 64 + co]);
  } else if (bid < 872) {
    int tid = (bid - 864) * 256 + threadIdx.x;  // 0..2047 = 16 batches * 128 out
    int bi = tid >> 7, co = tid & 127;
    float acc = bt[co];
    for (int e = 0; e < 256; ++e) {
      float tv = t[bi * 256 + e];
      acc += silu_f(tv) * Wt[e * 128 + co];
    }
    if (co < 64) scale_eff[bi * 64 + co] = 1.f + acc;
    else         shift[bi * 64 + (co - 64)] = acc;
  } else {
    int i = ((bid - 872) * 256 + threadIdx.x) * 8;
    if (i >= total) {
      if (i < total + 64) *(uint2v*)(a1 + i) = (uint2v){0u, 0u};   // zero row N
      return;
    }
    float4 va = *(const float4*)(x + i);
    float4 vb = *(const float4*)(x + i + 4);
    int c = i & 63;
    float4 ga = *(const float4*)(g1 + c), gb = *(const float4*)(g1 + c + 4);
    float4 ba = *(const float4*)(b1 + c), bbv = *(const float4*)(b1 + c + 4);
    float4 ma = *(const float4*)(m1 + c), mb = *(const float4*)(m1 + c + 4);
    float4 vva = *(const float4*)(v1 + c), vvb = *(const float4*)(v1 + c + 4);
    float z0 = silu_f((va.x - ma.x) * (ga.x * rsqrtf(vva.x + BN_EPS)) + ba.x);
    float z1 = silu_f((va.y - ma.y) * (ga.y * rsqrtf(vva.y + BN_EPS)) + ba.y);
    float z2 = silu_f((va.z - ma.z) * (ga.z * rsqrtf(vva.z + BN_EPS)) + ba.z);
    float z3 = silu_f((va.w - ma.w) * (ga.w * rsqrtf(vva.w + BN_EPS)) + ba.w);
    float z4 = silu_f((vb.x - mb.x) * (gb.x * rsqrtf(vvb.x + BN_EPS)) + bbv.x);
    float z5 = silu_f((vb.y - mb.y) * (gb.y * rsqrtf(vvb.y + BN_EPS)) + bbv.y);
    float z6 = silu_f((vb.z - mb.z) * (gb.z * rsqrtf(vvb.z + BN_EPS)) + bbv.z);
    float z7 = silu_f((vb.w - mb.w) * (gb.w * rsqrtf(vvb.w + BN_EPS)) + bbv.w);
    unsigned int w0 = (unsigned int)__builtin_amdgcn_cvt_pk_fp8_f32(z0, z1, 0, 0);
    w0 = (unsigned int)__builtin_amdgcn_cvt_pk_fp8_f32(z2, z3, (int)w0, 1);
    unsigned int w1 = (unsigned int)__builtin_amdgcn_cvt_pk_fp8_f32(z4, z5, 0, 0);
    w1 = (unsigned int)__builtin_amdgcn_cvt_pk_fp8_f32(z6, z7, (int)w1, 1);
    *(uint2v*)(a1 + i) = (uint2v){w0, w1};
  }
}

// ---- sparse conv, fp8: 64-node tile, reg-staged gather depth-3, lgkm-only barrier.
// Block = 256 threads / 4 waves. Wave w: rows (w>>1)*32..+31, cols (w&1)*32..+31.
// Staging: thread t covers row rL = wid*16 + (lane>>2) (fp8 row = 64 B), chunk q0=lane&3
// (16 B) -> 1 gather load/thread/tap; 4-lane group reads one full 64-B row (1 line).
// LDS [2][64][72]: stride-72 rows -> <=4-way bank alias, no XOR swizzle needed.
// Pipeline (R10-verified rotation): iter k:
//   DSWRITE(k+1)<-st[(k+1)%3] ; GLOAD(k+3)->st[(k+3)%3] rows rv[(k+1)&1] ;
//   LDVG(k+4)->rv[k&1] ; WLOAD(k+1)->wr[(k+1)&1] ; COMPUTE(k) ;
//   s_waitcnt lgkmcnt(0); s_barrier      (vmcnt NOT drained)
// MODE 0: reads idx/valid, nt-writes rows_enc for conv2; epilogue FiLM+bn2+silu -> fp8 a2
// MODE 1: reads rows_enc (1 load); epilogue +bias+residual -> f32 out
template <int MODE>
__global__ __launch_bounds__(256, 4) void conv_k(
    const unsigned char* __restrict__ act, const int* __restrict__ idx,
    const int* __restrict__ valid, int* __restrict__ rowse,
    const unsigned char* __restrict__ Wp,
    const float* __restrict__ bias,
    const float* __restrict__ scale_eff, const float* __restrict__ shift,
    const int* __restrict__ bidx,
    const float* __restrict__ g2, const float* __restrict__ b2,
    const float* __restrict__ m2, const float* __restrict__ v2,
    const float* __restrict__ xres,
    unsigned char* __restrict__ out8, float* __restrict__ out_f, int N) {
  __shared__ unsigned char lds[2][64 * LSTRIDE];

  if (MODE == 0 && blockIdx.x == 0 && threadIdx.x < 64) {
    out8[(size_t)N * 64 + threadIdx.x] = 0;  // zero row for conv2's invalid taps
  }
  const int tid = threadIdx.x;
  const int lane = tid & 63;
  const int wid = tid >> 6;
  const int half = lane >> 5;   // 0/1
  const int r32 = lane & 31;
  const int n0 = blockIdx.x * 64;

  const int q0 = lane & 3;            // 16B chunk within the 64B row
  const int rL = wid * 16 + (lane >> 2);  // row this thread stages
  const int nS = min(n0 + rL, N - 1);     // node for that row
  const int RH = wid >> 1;
  const int cb = wid & 1;

  f32x16 acc;
#pragma unroll
  for (int i = 0; i < 16; ++i) acc[i] = 0.f;

  int rvA, rvB;            // gather row per thread, slot = tap&1
  lv2 st0, st1, st2;       // staged 16B chunks, slot = tap%3
  long wrA[4], wrB[4];     // W fragments (8B each), parity = tap&1

#define LDVG(kk) ({ \
    int _r; \
    if (MODE == 0) { \
      int _v = valid[(size_t)(kk) * N + nS]; \
      int _g = idx[(size_t)(kk) * N + nS]; \
      _r = _v ? _g : N; \
      if (q0 == 0) __builtin_nontemporal_store(_r, rowse + (size_t)(kk) * N + nS); \
    } else { \
      _r = rowse[(size_t)(kk) * N + nS]; \
    } \
    _r; })

#define GLOAD(st, rv) do { \
    st = *(const lv2*)(act + (size_t)(rv) * 64 + q0 * 16); \
  } while (0)

#define DSWRITE(buf, st) do { \
    unsigned char* _p = &lds[buf][rL * LSTRIDE + q0 * 16]; \
    *(long*)_p = st.x; \
    *(long*)(_p + 8) = st.y; \
  } while (0)

#define WLOAD(kk, wr) do { \
    _Pragma("unroll") \
    for (int ks = 0; ks < 4; ++ks) \
      wr[ks] = ((const long*)Wp)[((size_t)(kk) * 8 + ks * 2 + cb) * 64 + lane]; \
  } while (0)

#define COMPUTE(buf, wr) do { \
    _Pragma("unroll") \
    for (int ks = 0; ks < 4; ++ks) { \
      long av = *(const long*)(&lds[buf][(RH * 32 + r32) * LSTRIDE + ks * 16 + half * 8]); \
      acc = __builtin_amdgcn_mfma_f32_32x32x16_fp8_fp8(av, wr[ks], acc, 0, 0, 0); \
    } } while (0)

#define BARRIER() do { \
    asm volatile("s_waitcnt lgkmcnt(0)" ::: "memory"); \
    __builtin_amdgcn_s_barrier(); \
  } while (0)

  // prologue: st0<-tap0, st1<-tap1, st2<-tap2; rvB<-rows(3); wrA<-W(0)
  rvA = LDVG(0);
  GLOAD(st0, rvA);
  rvB = LDVG(1);
  GLOAD(st1, rvB);
  rvA = LDVG(2);
  GLOAD(st2, rvA);
  rvB = LDVG(3);
  rvA = 0;
  WLOAD(0, wrA);
  DSWRITE(0, st0);        // compiler inserts counted vmcnt for st0 here
  BARRIER();

#pragma unroll
  for (int k = 0; k < KOFF; ++k) {
    if (k + 1 < KOFF) {          // DSWRITE(k+1) <- st[(k+1)%3] into buf (k+1)&1
      const int s = (k + 1) % 3;
      if (s == 0)      DSWRITE((k + 1) & 1, st0);
      else if (s == 1) DSWRITE((k + 1) & 1, st1);
      else             DSWRITE((k + 1) & 1, st2);
    }
    if (k + 3 < KOFF) {          // GLOAD(k+3) -> st[(k+3)%3], rows in rv[(k+1)&1]
      const int s = (k + 3) % 3;
      if ((k + 1) & 1) {
        if (s == 0) GLOAD(st0, rvB); else if (s == 1) GLOAD(st1, rvB); else GLOAD(st2, rvB);
      } else {
        if (s == 0) GLOAD(st0, rvA); else if (s == 1) GLOAD(st1, rvA); else GLOAD(st2, rvA);
      }
    }
    if (k + 4 < KOFF) {          // LDVG(k+4) -> rv[k&1]
      if (k & 1) rvB = LDVG(k + 4); else rvA = LDVG(k + 4);
    }
    if (k + 1 < KOFF) {
      if ((k + 1) & 1) WLOAD(k + 1, wrB); else WLOAD(k + 1, wrA);
    }
    if (k & 1) COMPUTE(1, wrB); else COMPUTE(0, wrA);
    if (k + 1 < KOFF) BARRIER();
  }
#undef LDVG
#undef GLOAD
#undef DSWRITE
#undef WLOAD
#undef COMPUTE
#undef BARRIER

  // D frag: col = cb*32 + r32, row = RH*32 + (r&3) + 8*(r>>2) + 4*half (dtype-independent)
  if (MODE == 0) {
    const int c = cb * 32 + r32;
    float bb = bias[c];
    float s2v = g2[c] * rsqrtf(v2[c] + BN_EPS);
    float o2v = b2[c] - m2[c] * s2v;
#pragma unroll
    for (int r = 0; r < 16; ++r) {
      int rowD = (r & 3) + 8 * (r >> 2) + 4 * half;
      int n = n0 + RH * 32 + rowD;
      if (n < N) {
        int bi = bidx[n];
        float h = acc[r] + bb;
        h = scale_eff[bi * 64 + c] * h + shift[bi * 64 + c];
        float z = h * s2v + o2v;
        out8[(size_t)n * 64 + c] = f2fp8(silu_f(z));
      }
    }
  } else {
    const int c = cb * 32 + r32;
    float bb = bias[c];
#pragma unroll
    for (int r = 0; r < 16; ++r) {
      int rowD = (r & 3) + 8 * (r >> 2) + 4 * half;
      int n = n0 + RH * 32 + rowD;
      if (n < N) {
        out_f[(size_t)n * 64 + c] = acc[r] + bb + xres[(size_t)n * 64 + c];
      }
    }
  }
}

extern "C" void kernel_launch(void* const* d_in, const int* in_sizes, int n_in,
                              void* d_out, int out_size, void* d_ws, size_t ws_size,
                              hipStream_t stream) {
  const float* x    = (const float*)d_in[0];
  const float* t    = (const float*)d_in[1];
  const int*   b    = (const int*)d_in[2];
  const int*   kidx = (const int*)d_in[3];
  const int*   kval = (const int*)d_in[4];
  const float* bn1g = (const float*)d_in[5];
  const float* bn1b = (const float*)d_in[6];
  const float* bn1m = (const float*)d_in[7];
  const float* bn1v = (const float*)d_in[8];
  const float* W1   = (const float*)d_in[9];
  const float* b1c  = (const float*)d_in[10];
  const float* bn2g = (const float*)d_in[11];
  const float* bn2b = (const float*)d_in[12];
  const float* bn2m = (const float*)d_in[13];
  const float* bn2v = (const float*)d_in[14];
  const float* W2   = (const float*)d_in[15];
  const float* b2c  = (const float*)d_in[16];
  const float* Wt   = (const float*)d_in[17];
  const float* bt   = (const float*)d_in[18];
  float* out = (float*)d_out;

  const int N = in_sizes[2];        // 100000
  const int total = N * 64;

  // workspace layout (bytes); act buffers have N+1 rows (row N = zeros), fp8
  char* ws = (char*)d_ws;
  size_t actB = ((size_t)(N + 1) * 64 + 255) & ~(size_t)255;       // 6.4 MB
  unsigned char* a1 = (unsigned char*)ws;
  unsigned char* a2 = (unsigned char*)(ws + actB);
  const size_t wpackB = (size_t)KOFF * 8 * 64 * 8;                 // 110592 B
  unsigned char* W1p = (unsigned char*)(ws + 2 * actB);
  unsigned char* W2p = (unsigned char*)(ws + 2 * actB + wpackB);
  float* scale_eff = (float*)(ws + 2 * actB + 2 * wpackB);
  float* shiftp    = scale_eff + 16 * 64;
  int*   rows_enc  = (int*)(ws + 2 * actB + 2 * wpackB + 8192);    // 10.8 MB

  int bnblk = (total / 8 + 8 + 255) / 256;
  prep_all<<<872 + bnblk, 256, 0, stream>>>(t, Wt, bt, scale_eff, shiftp,
                                            W1, W2, W1p, W2p,
                                            x, bn1g, bn1b, bn1m, bn1v, a1, total);

  int nblk = (N + 63) / 64;
  conv_k<0><<<nblk, 256, 0, stream>>>(a1, kidx, kval, rows_enc, W1p, b1c, scale_eff,
                                      shiftp, b, bn2g, bn2b, bn2m, bn2v,
                                      nullptr, a2, nullptr, N);
  conv_k<1><<<nblk, 256, 0, stream>>>(a2, nullptr, nullptr, rows_enc, W2p, b2c, nullptr,
                                      nullptr, nullptr, nullptr, nullptr, nullptr,
                                      nullptr, x, nullptr, out, N);
}

// Round 14
// 112.870 us; speedup vs baseline: 1.5622x; 1.1293x over previous
//
#include <hip/hip_runtime.h>

typedef __attribute__((ext_vector_type(16))) float f32x16;
typedef __attribute__((ext_vector_type(2))) long lv2;
typedef __attribute__((ext_vector_type(2))) unsigned int uint2v;

#define BN_EPS 1e-5f
#define KOFF 27
#define LSTRIDE 72   // act LDS row stride in bytes (64B row + 8B pad)

static __device__ __forceinline__ float silu_f(float z) {
  return z / (1.f + __expf(-z));
}

// f32 -> fp8 e4m3 (OCP on gfx950), RNE+sat via HW cvt
static __device__ __forceinline__ unsigned char f2fp8(float v) {
  unsigned int p = (unsigned int)__builtin_amdgcn_cvt_pk_fp8_f32(v, 0.f, 0, 0);
  return (unsigned char)(p & 0xffu);
}

// ---- fused prep:
// [0,864)   : pack W1+W2 -> fp8 MFMA B-frag order (32x32x16 fp8, K=16)
//             frag f=ks*2+cb: lane l byte j <- W[k][ks*16+(l>>5)*8+j][cb*32+(l&31)]
// [864,872) : time MLP (f32)
// [872,...) : a1 = fp8(silu(bn1(x))), 8 elems/thread; zero row N
__global__ void prep_all(const float* __restrict__ t, const float* __restrict__ Wt,
                         const float* __restrict__ bt,
                         float* __restrict__ scale_eff, float* __restrict__ shift,
                         const float* __restrict__ W1, const float* __restrict__ W2,
                         unsigned char* __restrict__ Wp1, unsigned char* __restrict__ Wp2,
                         const float* __restrict__ x, const float* __restrict__ g1,
                         const float* __restrict__ b1, const float* __restrict__ m1,
                         const float* __restrict__ v1, unsigned char* __restrict__ a1,
                         int total) {
  const int bid = blockIdx.x;
  if (bid < 864) {
    int tid = bid * 256 + threadIdx.x;          // 0 .. 221183 = 2*tot
    const int tot = KOFF * 8 * 64 * 8;          // 110592 bytes per W
    const float* W = W1;
    unsigned char* Wp = Wp1;
    if (tid >= tot) { tid -= tot; W = W2; Wp = Wp2; }
    int j = tid & 7, lane = (tid >> 3) & 63, f = (tid >> 9) & 7, k = tid >> 12;
    int ci = (f >> 1) * 16 + (lane >> 5) * 8 + j;
    int co = (f & 1) * 32 + (lane & 31);
    Wp[tid] = f2fp8(W[(k * 64 + ci) * 64 + co]);
  } else if (bid < 872) {
    int tid = (bid - 864) * 256 + threadIdx.x;  // 0..2047 = 16 batches * 128 out
    int bi = tid >> 7, co = tid & 127;
    float acc = bt[co];
    for (int e = 0; e < 256; ++e) {
      float tv = t[bi * 256 + e];
      acc += silu_f(tv) * Wt[e * 128 + co];
    }
    if (co < 64) scale_eff[bi * 64 + co] = 1.f + acc;
    else         shift[bi * 64 + (co - 64)] = acc;
  } else {
    int i = ((bid - 872) * 256 + threadIdx.x) * 8;
    if (i >= total) {
      if (i < total + 64) *(uint2v*)(a1 + i) = (uint2v){0u, 0u};   // zero row N
      return;
    }
    float4 va = *(const float4*)(x + i);
    float4 vb = *(const float4*)(x + i + 4);
    int c = i & 63;
    float4 ga = *(const float4*)(g1 + c), gb = *(const float4*)(g1 + c + 4);
    float4 ba = *(const float4*)(b1 + c), bbv = *(const float4*)(b1 + c + 4);
    float4 ma = *(const float4*)(m1 + c), mb = *(const float4*)(m1 + c + 4);
    float4 vva = *(const float4*)(v1 + c), vvb = *(const float4*)(v1 + c + 4);
    float z0 = silu_f((va.x - ma.x) * (ga.x * rsqrtf(vva.x + BN_EPS)) + ba.x);
    float z1 = silu_f((va.y - ma.y) * (ga.y * rsqrtf(vva.y + BN_EPS)) + ba.y);
    float z2 = silu_f((va.z - ma.z) * (ga.z * rsqrtf(vva.z + BN_EPS)) + ba.z);
    float z3 = silu_f((va.w - ma.w) * (ga.w * rsqrtf(vva.w + BN_EPS)) + ba.w);
    float z4 = silu_f((vb.x - mb.x) * (gb.x * rsqrtf(vvb.x + BN_EPS)) + bbv.x);
    float z5 = silu_f((vb.y - mb.y) * (gb.y * rsqrtf(vvb.y + BN_EPS)) + bbv.y);
    float z6 = silu_f((vb.z - mb.z) * (gb.z * rsqrtf(vvb.z + BN_EPS)) + bbv.z);
    float z7 = silu_f((vb.w - mb.w) * (gb.w * rsqrtf(vvb.w + BN_EPS)) + bbv.w);
    unsigned int w0 = (unsigned int)__builtin_amdgcn_cvt_pk_fp8_f32(z0, z1, 0, 0);
    w0 = (unsigned int)__builtin_amdgcn_cvt_pk_fp8_f32(z2, z3, (int)w0, 1);
    unsigned int w1 = (unsigned int)__builtin_amdgcn_cvt_pk_fp8_f32(z4, z5, 0, 0);
    w1 = (unsigned int)__builtin_amdgcn_cvt_pk_fp8_f32(z6, z7, (int)w1, 1);
    *(uint2v*)(a1 + i) = (uint2v){w0, w1};
  }
}

// ---- sparse conv, fp8, W staged through LDS (TA-offload).
// Block = 256 threads / 4 waves / 64 nodes. Wave w: rows (w>>1)*32..+31, cols (w&1)*32..+31.
// Act staging: thread covers row rL = wid*16 + (lane>>2), chunk q0=lane&3 (16B)
//   -> 1 gather load/thread/tap. LDS act ring [2][64][72] (stride-72: 2-way alias, free).
// W staging: thread loads 16B of the 4KB tap-tile (coalesced) -> reg -> LDS ring [2][4096];
//   COMPUTE reads frags via ds_read_b64 (consecutive 512B/frag, conflict-free).
// Per-wave-tap TA instructions: GLOAD 1 + LDVG 1(+store in MODE 0) + WGLOAD 1 = 3.
// Pipeline at iter k (fully unrolled, R13-verified act rotation + parity W ring):
//   DSWRITE(k+1)<-st[(k+1)%3] ; DSWRITE_W(k+1)<-wst[(k+1)&1] ;
//   WGLOAD(k+2)->wst[k&1] ; GLOAD(k+3)->st[(k+3)%3] rows rv[(k+1)&1] ;
//   LDVG(k+4)->rv[k&1] ; COMPUTE(k) ; s_waitcnt lgkmcnt(0); s_barrier  (vmcnt NOT drained)
// MODE 0: reads idx/valid, nt-writes rows_enc for conv2; epilogue FiLM+bn2+silu -> fp8 a2
// MODE 1: reads rows_enc (1 load); epilogue +bias+residual -> f32 out
template <int MODE>
__global__ __launch_bounds__(256, 6) void conv_k(
    const unsigned char* __restrict__ act, const int* __restrict__ idx,
    const int* __restrict__ valid, int* __restrict__ rowse,
    const unsigned char* __restrict__ Wp,
    const float* __restrict__ bias,
    const float* __restrict__ scale_eff, const float* __restrict__ shift,
    const int* __restrict__ bidx,
    const float* __restrict__ g2, const float* __restrict__ b2,
    const float* __restrict__ m2, const float* __restrict__ v2,
    const float* __restrict__ xres,
    unsigned char* __restrict__ out8, float* __restrict__ out_f, int N) {
  __shared__ unsigned char ldsA[2][64 * LSTRIDE];
  __shared__ unsigned char ldsW[2][4096];

  if (MODE == 0 && blockIdx.x == 0 && threadIdx.x < 64) {
    out8[(size_t)N * 64 + threadIdx.x] = 0;  // zero row for conv2's invalid taps
  }
  const int tid = threadIdx.x;
  const int lane = tid & 63;
  const int wid = tid >> 6;
  const int half = lane >> 5;   // 0/1
  const int r32 = lane & 31;
  const int n0 = blockIdx.x * 64;

  const int q0 = lane & 3;                // 16B chunk within the 64B act row
  const int rL = wid * 16 + (lane >> 2);  // act row this thread stages
  const int nS = min(n0 + rL, N - 1);     // node for that row
  const int RH = wid >> 1;
  const int cb = wid & 1;

  f32x16 acc;
#pragma unroll
  for (int i = 0; i < 16; ++i) acc[i] = 0.f;

  int rvA, rvB;            // gather row per thread, slot = tap&1
  lv2 st0, st1, st2;       // staged act chunks, slot = tap%3
  lv2 wstA, wstB;          // staged W chunk (16B/thread), slot = tap&1

#define LDVG(kk) ({ \
    int _r; \
    if (MODE == 0) { \
      int _v = valid[(size_t)(kk) * N + nS]; \
      int _g = idx[(size_t)(kk) * N + nS]; \
      _r = _v ? _g : N; \
      if (q0 == 0) __builtin_nontemporal_store(_r, rowse + (size_t)(kk) * N + nS); \
    } else { \
      _r = rowse[(size_t)(kk) * N + nS]; \
    } \
    _r; })

#define GLOAD(st, rv) do { \
    st = *(const lv2*)(act + (size_t)(rv) * 64 + q0 * 16); \
  } while (0)

#define WGLOAD(kk, wst) do { \
    wst = *(const lv2*)(Wp + (size_t)(kk) * 4096 + tid * 16); \
  } while (0)

#define DSWRITE(buf, st) do { \
    unsigned char* _p = &ldsA[buf][rL * LSTRIDE + q0 * 16]; \
    *(long*)_p = st.x; \
    *(long*)(_p + 8) = st.y; \
  } while (0)

#define DSWRITE_W(buf, wst) do { \
    unsigned char* _p = &ldsW[buf][tid * 16]; \
    *(long*)_p = wst.x; \
    *(long*)(_p + 8) = wst.y; \
  } while (0)

#define COMPUTE(buf) do { \
    _Pragma("unroll") \
    for (int ks = 0; ks < 4; ++ks) { \
      long av = *(const long*)(&ldsA[buf][(RH * 32 + r32) * LSTRIDE + ks * 16 + half * 8]); \
      long wv = *(const long*)(&ldsW[buf][((ks * 2 + cb) * 64 + lane) * 8]); \
      acc = __builtin_amdgcn_mfma_f32_32x32x16_fp8_fp8(av, wv, acc, 0, 0, 0); \
    } } while (0)

#define BARRIER() do { \
    asm volatile("s_waitcnt lgkmcnt(0)" ::: "memory"); \
    __builtin_amdgcn_s_barrier(); \
  } while (0)

  // prologue: act st0/st1/st2 <- taps 0/1/2; rvB <- rows(3); W taps 0,1 -> regs
  rvA = LDVG(0);
  GLOAD(st0, rvA);
  rvB = LDVG(1);
  GLOAD(st1, rvB);
  rvA = LDVG(2);
  GLOAD(st2, rvA);
  rvB = LDVG(3);
  rvA = 0;
  WGLOAD(0, wstA);
  WGLOAD(1, wstB);
  DSWRITE(0, st0);        // compiler inserts counted vmcnt for st0/wstA here
  DSWRITE_W(0, wstA);
  BARRIER();

#pragma unroll
  for (int k = 0; k < KOFF; ++k) {
    if (k + 1 < KOFF) {          // stage tap k+1 into LDS slot (k+1)&1
      const int s = (k + 1) % 3;
      if (s == 0)      DSWRITE((k + 1) & 1, st0);
      else if (s == 1) DSWRITE((k + 1) & 1, st1);
      else             DSWRITE((k + 1) & 1, st2);
      if ((k + 1) & 1) DSWRITE_W(1, wstB); else DSWRITE_W(0, wstA);
    }
    if (k + 2 < KOFF) {          // W tap k+2 -> wst[k&1]
      if (k & 1) WGLOAD(k + 2, wstB); else WGLOAD(k + 2, wstA);
    }
    if (k + 3 < KOFF) {          // act tap k+3 -> st[(k+3)%3], rows in rv[(k+1)&1]
      const int s = (k + 3) % 3;
      if ((k + 1) & 1) {
        if (s == 0) GLOAD(st0, rvB); else if (s == 1) GLOAD(st1, rvB); else GLOAD(st2, rvB);
      } else {
        if (s == 0) GLOAD(st0, rvA); else if (s == 1) GLOAD(st1, rvA); else GLOAD(st2, rvA);
      }
    }
    if (k + 4 < KOFF) {          // rows(k+4) -> rv[k&1]
      if (k & 1) rvB = LDVG(k + 4); else rvA = LDVG(k + 4);
    }
    COMPUTE(k & 1);
    if (k + 1 < KOFF) BARRIER();
  }
#undef LDVG
#undef GLOAD
#undef WGLOAD
#undef DSWRITE
#undef DSWRITE_W
#undef COMPUTE
#undef BARRIER

  // D frag: col = cb*32 + r32, row = RH*32 + (r&3) + 8*(r>>2) + 4*half (dtype-independent)
  if (MODE == 0) {
    const int c = cb * 32 + r32;
    float bb = bias[c];
    float s2v = g2[c] * rsqrtf(v2[c] + BN_EPS);
    float o2v = b2[c] - m2[c] * s2v;
#pragma unroll
    for (int r = 0; r < 16; ++r) {
      int rowD = (r & 3) + 8 * (r >> 2) + 4 * half;
      int n = n0 + RH * 32 + rowD;
      if (n < N) {
        int bi = bidx[n];
        float h = acc[r] + bb;
        h = scale_eff[bi * 64 + c] * h + shift[bi * 64 + c];
        float z = h * s2v + o2v;
        out8[(size_t)n * 64 + c] = f2fp8(silu_f(z));
      }
    }
  } else {
    const int c = cb * 32 + r32;
    float bb = bias[c];
#pragma unroll
    for (int r = 0; r < 16; ++r) {
      int rowD = (r & 3) + 8 * (r >> 2) + 4 * half;
      int n = n0 + RH * 32 + rowD;
      if (n < N) {
        out_f[(size_t)n * 64 + c] = acc[r] + bb + xres[(size_t)n * 64 + c];
      }
    }
  }
}

extern "C" void kernel_launch(void* const* d_in, const int* in_sizes, int n_in,
                              void* d_out, int out_size, void* d_ws, size_t ws_size,
                              hipStream_t stream) {
  const float* x    = (const float*)d_in[0];
  const float* t    = (const float*)d_in[1];
  const int*   b    = (const int*)d_in[2];
  const int*   kidx = (const int*)d_in[3];
  const int*   kval = (const int*)d_in[4];
  const float* bn1g = (const float*)d_in[5];
  const float* bn1b = (const float*)d_in[6];
  const float* bn1m = (const float*)d_in[7];
  const float* bn1v = (const float*)d_in[8];
  const float* W1   = (const float*)d_in[9];
  const float* b1c  = (const float*)d_in[10];
  const float* bn2g = (const float*)d_in[11];
  const float* bn2b = (const float*)d_in[12];
  const float* bn2m = (const float*)d_in[13];
  const float* bn2v = (const float*)d_in[14];
  const float* W2   = (const float*)d_in[15];
  const float* b2c  = (const float*)d_in[16];
  const float* Wt   = (const float*)d_in[17];
  const float* bt   = (const float*)d_in[18];
  float* out = (float*)d_out;

  const int N = in_sizes[2];        // 100000
  const int total = N * 64;

  // workspace layout (bytes); act buffers have N+1 rows (row N = zeros), fp8
  char* ws = (char*)d_ws;
  size_t actB = ((size_t)(N + 1) * 64 + 255) & ~(size_t)255;       // 6.4 MB
  unsigned char* a1 = (unsigned char*)ws;
  unsigned char* a2 = (unsigned char*)(ws + actB);
  const size_t wpackB = (size_t)KOFF * 8 * 64 * 8;                 // 110592 B
  unsigned char* W1p = (unsigned char*)(ws + 2 * actB);
  unsigned char* W2p = (unsigned char*)(ws + 2 * actB + wpackB);
  float* scale_eff = (float*)(ws + 2 * actB + 2 * wpackB);
  float* shiftp    = scale_eff + 16 * 64;
  int*   rows_enc  = (int*)(ws + 2 * actB + 2 * wpackB + 8192);    // 10.8 MB

  int bnblk = (total / 8 + 8 + 255) / 256;
  prep_all<<<872 + bnblk, 256, 0, stream>>>(t, Wt, bt, scale_eff, shiftp,
                                            W1, W2, W1p, W2p,
                                            x, bn1g, bn1b, bn1m, bn1v, a1, total);

  int nblk = (N + 63) / 64;
  conv_k<0><<<nblk, 256, 0, stream>>>(a1, kidx, kval, rows_enc, W1p, b1c, scale_eff,
                                      shiftp, b, bn2g, bn2b, bn2m, bn2v,
                                      nullptr, a2, nullptr, N);
  conv_k<1><<<nblk, 256, 0, stream>>>(a2, nullptr, nullptr, rows_enc, W2p, b2c, nullptr,
                                      nullptr, nullptr, nullptr, nullptr, nullptr,
                                      nullptr, x, nullptr, out, N);
}

// Round 15
// 100.115 us; speedup vs baseline: 1.7612x; 1.1274x over previous
//
#include <hip/hip_runtime.h>

typedef __attribute__((ext_vector_type(16))) float f32x16;
typedef __attribute__((ext_vector_type(2))) long lv2;
typedef __attribute__((ext_vector_type(2))) unsigned int uint2v;

#define BN_EPS 1e-5f
#define KOFF 27
#define LSTRIDE 72   // act LDS row stride in bytes (64B row + 8B pad -> 2-way alias, free)

static __device__ __forceinline__ float silu_f(float z) {
  return z / (1.f + __expf(-z));
}

// f32 -> fp8 e4m3 (OCP on gfx950), RNE+sat via HW cvt
static __device__ __forceinline__ unsigned char f2fp8(float v) {
  unsigned int p = (unsigned int)__builtin_amdgcn_cvt_pk_fp8_f32(v, 0.f, 0, 0);
  return (unsigned char)(p & 0xffu);
}

// ---- fused prep:
// [0,864)   : pack W1+W2 -> fp8 MFMA B-frag order (32x32x16 fp8, K=16)
//             frag f=ks*2+cb: lane l byte j <- W[k][ks*16+(l>>5)*8+j][cb*32+(l&31)]
// [864,872) : time MLP (f32)
// [872,...) : a1 = fp8(silu(bn1(x))), 8 elems/thread; zero row N
__global__ void prep_all(const float* __restrict__ t, const float* __restrict__ Wt,
                         const float* __restrict__ bt,
                         float* __restrict__ scale_eff, float* __restrict__ shift,
                         const float* __restrict__ W1, const float* __restrict__ W2,
                         unsigned char* __restrict__ Wp1, unsigned char* __restrict__ Wp2,
                         const float* __restrict__ x, const float* __restrict__ g1,
                         const float* __restrict__ b1, const float* __restrict__ m1,
                         const float* __restrict__ v1, unsigned char* __restrict__ a1,
                         int total) {
  const int bid = blockIdx.x;
  if (bid < 864) {
    int tid = bid * 256 + threadIdx.x;          // 0 .. 221183 = 2*tot
    const int tot = KOFF * 8 * 64 * 8;          // 110592 bytes per W
    const float* W = W1;
    unsigned char* Wp = Wp1;
    if (tid >= tot) { tid -= tot; W = W2; Wp = Wp2; }
    int j = tid & 7, lane = (tid >> 3) & 63, f = (tid >> 9) & 7, k = tid >> 12;
    int ci = (f >> 1) * 16 + (lane >> 5) * 8 + j;
    int co = (f & 1) * 32 + (lane & 31);
    Wp[tid] = f2fp8(W[(k * 64 + ci) * 64 + co]);
  } else if (bid < 872) {
    int tid = (bid - 864) * 256 + threadIdx.x;  // 0..2047 = 16 batches * 128 out
    int bi = tid >> 7, co = tid & 127;
    float acc = bt[co];
    for (int e = 0; e < 256; ++e) {
      float tv = t[bi * 256 + e];
      acc += silu_f(tv) * Wt[e * 128 + co];
    }
    if (co < 64) scale_eff[bi * 64 + co] = 1.f + acc;
    else         shift[bi * 64 + (co - 64)] = acc;
  } else {
    int i = ((bid - 872) * 256 + threadIdx.x) * 8;
    if (i >= total) {
      if (i < total + 64) *(uint2v*)(a1 + i) = (uint2v){0u, 0u};   // zero row N
      return;
    }
    float4 va = *(const float4*)(x + i);
    float4 vb = *(const float4*)(x + i + 4);
    int c = i & 63;
    float4 ga = *(const float4*)(g1 + c), gb = *(const float4*)(g1 + c + 4);
    float4 ba = *(const float4*)(b1 + c), bbv = *(const float4*)(b1 + c + 4);
    float4 ma = *(const float4*)(m1 + c), mb = *(const float4*)(m1 + c + 4);
    float4 vva = *(const float4*)(v1 + c), vvb = *(const float4*)(v1 + c + 4);
    float z0 = silu_f((va.x - ma.x) * (ga.x * rsqrtf(vva.x + BN_EPS)) + ba.x);
    float z1 = silu_f((va.y - ma.y) * (ga.y * rsqrtf(vva.y + BN_EPS)) + ba.y);
    float z2 = silu_f((va.z - ma.z) * (ga.z * rsqrtf(vva.z + BN_EPS)) + ba.z);
    float z3 = silu_f((va.w - ma.w) * (ga.w * rsqrtf(vva.w + BN_EPS)) + ba.w);
    float z4 = silu_f((vb.x - mb.x) * (gb.x * rsqrtf(vvb.x + BN_EPS)) + bbv.x);
    float z5 = silu_f((vb.y - mb.y) * (gb.y * rsqrtf(vvb.y + BN_EPS)) + bbv.y);
    float z6 = silu_f((vb.z - mb.z) * (gb.z * rsqrtf(vvb.z + BN_EPS)) + bbv.z);
    float z7 = silu_f((vb.w - mb.w) * (gb.w * rsqrtf(vvb.w + BN_EPS)) + bbv.w);
    unsigned int w0 = (unsigned int)__builtin_amdgcn_cvt_pk_fp8_f32(z0, z1, 0, 0);
    w0 = (unsigned int)__builtin_amdgcn_cvt_pk_fp8_f32(z2, z3, (int)w0, 1);
    unsigned int w1 = (unsigned int)__builtin_amdgcn_cvt_pk_fp8_f32(z4, z5, 0, 0);
    w1 = (unsigned int)__builtin_amdgcn_cvt_pk_fp8_f32(z6, z7, (int)w1, 1);
    *(uint2v*)(a1 + i) = (uint2v){w0, w1};
  }
}

// ---- sparse conv, fp8, W staged through LDS + grouped index loads via LDS ring.
// Block = 256 threads / 4 waves / 64 nodes. Wave w: rows (w>>1)*32..+31, cols (w&1)*32..+31.
// Act staging: thread covers row rL = wid*16 + (lane>>2), chunk q0=lane&3 (16B).
// Index loads: ONE instr/wave per 2 taps covers (idx,valid)x(2 taps)x(16 rows):
//   role q0&1 = array (idx/valid), q0>>1 = tap-in-group; values go to 3-slot LDS ring
//   rI/rV[g%3][2][64]; gather-time ring-read (broadcast b32 x2) + cndmask -> rv.
//   GRPLOAD at even k (g=(k+6)/2, k<=20) -> reg; RINGWRITE at odd k (g=(k+5)/2, k<=21);
//   read of tap t at slot (t>>1)%3 (rotation hand-verified; tap-27 load clamped, unread).
// Steady-state VMEM/wave/tap: GLOAD 1 + grouped-idx 0.5 + WGLOAD 1 = 2.5 (both convs).
// Pipeline at iter k (fully unrolled, R14-verified act/W rotation):
//   DSWRITE(k+1)<-st[(k+1)%3] ; DSWRITE_W(k+1)<-wst[(k+1)&1] ; GRP/RING per parity ;
//   WGLOAD(k+2)->wst[k&1] ; GLOAD(k+3)<-ring ; COMPUTE(k) ;
//   s_waitcnt lgkmcnt(0); s_barrier   (vmcnt NOT drained)
// MODE 0: epilogue FiLM+bn2+silu -> fp8 a2 (block 0 zeroes a2 row N)
// MODE 1: epilogue +bias+residual -> f32 out
template <int MODE>
__global__ __launch_bounds__(256, 6) void conv_k(
    const unsigned char* __restrict__ act, const int* __restrict__ idx,
    const int* __restrict__ valid,
    const unsigned char* __restrict__ Wp,
    const float* __restrict__ bias,
    const float* __restrict__ scale_eff, const float* __restrict__ shift,
    const int* __restrict__ bidx,
    const float* __restrict__ g2, const float* __restrict__ b2,
    const float* __restrict__ m2, const float* __restrict__ v2,
    const float* __restrict__ xres,
    unsigned char* __restrict__ out8, float* __restrict__ out_f, int N) {
  __shared__ unsigned char ldsA[2][64 * LSTRIDE];
  __shared__ unsigned char ldsW[2][4096];
  __shared__ int rI[3][2][64];
  __shared__ int rV[3][2][64];

  if (MODE == 0 && blockIdx.x == 0 && threadIdx.x < 64) {
    out8[(size_t)N * 64 + threadIdx.x] = 0;  // zero row for conv2's invalid taps
  }
  const int tid = threadIdx.x;
  const int lane = tid & 63;
  const int wid = tid >> 6;
  const int half = lane >> 5;   // 0/1
  const int r32 = lane & 31;
  const int n0 = blockIdx.x * 64;

  const int q0 = lane & 3;                // 16B chunk within the 64B act row
  const int rL = wid * 16 + (lane >> 2);  // act row this thread stages
  const int nS = min(n0 + rL, N - 1);     // node for that row
  const int RH = wid >> 1;
  const int cb = wid & 1;

  f32x16 acc;
#pragma unroll
  for (int i = 0; i < 16; ++i) acc[i] = 0.f;

  lv2 st0, st1, st2;       // staged act chunks, slot = tap%3
  lv2 wstA, wstB;          // staged W chunk (16B/thread), slot = tap&1
  int gr = 0;              // grouped-index staging register

  // one instr: role (q0&1) picks array, (q0>>1) picks tap within group g
#define GRPLOAD(g) do { \
    int tp = min(2 * (g) + (q0 >> 1), KOFF - 1); \
    const int* bp = (q0 & 1) ? valid : idx; \
    gr = bp[(size_t)tp * N + nS]; \
  } while (0)

#define RINGWRITE(g) do { \
    int* p = (q0 & 1) ? &rV[(g) % 3][q0 >> 1][rL] : &rI[(g) % 3][q0 >> 1][rL]; \
    *p = gr; \
  } while (0)

#define RINGREAD(t) \
    (rV[((t) >> 1) % 3][(t) & 1][rL] ? rI[((t) >> 1) % 3][(t) & 1][rL] : N)

#define GLOAD(st, rv) do { \
    st = *(const lv2*)(act + (size_t)(rv) * 64 + q0 * 16); \
  } while (0)

#define WGLOAD(kk, wst) do { \
    wst = *(const lv2*)(Wp + (size_t)(kk) * 4096 + tid * 16); \
  } while (0)

#define DSWRITE(buf, st) do { \
    unsigned char* _p = &ldsA[buf][rL * LSTRIDE + q0 * 16]; \
    *(long*)_p = st.x; \
    *(long*)(_p + 8) = st.y; \
  } while (0)

#define DSWRITE_W(buf, wst) do { \
    unsigned char* _p = &ldsW[buf][tid * 16]; \
    *(long*)_p = wst.x; \
    *(long*)(_p + 8) = wst.y; \
  } while (0)

#define COMPUTE(buf) do { \
    _Pragma("unroll") \
    for (int ks = 0; ks < 4; ++ks) { \
      long av = *(const long*)(&ldsA[buf][(RH * 32 + r32) * LSTRIDE + ks * 16 + half * 8]); \
      long wv = *(const long*)(&ldsW[buf][((ks * 2 + cb) * 64 + lane) * 8]); \
      acc = __builtin_amdgcn_mfma_f32_32x32x16_fp8_fp8(av, wv, acc, 0, 0, 0); \
    } } while (0)

#define BARRIER() do { \
    asm volatile("s_waitcnt lgkmcnt(0)" ::: "memory"); \
    __builtin_amdgcn_s_barrier(); \
  } while (0)

  // prologue: index groups 0,1,2 (taps 0..5) -> ring; then gather taps 0..2; W 0,1
  GRPLOAD(0); RINGWRITE(0);
  GRPLOAD(1); RINGWRITE(1);
  GRPLOAD(2); RINGWRITE(2);
  BARRIER();                 // ring visible
  {
    int rv0 = RINGREAD(0);
    GLOAD(st0, rv0);
    int rv1 = RINGREAD(1);
    GLOAD(st1, rv1);
    int rv2 = RINGREAD(2);
    GLOAD(st2, rv2);
  }
  WGLOAD(0, wstA);
  WGLOAD(1, wstB);
  DSWRITE(0, st0);           // compiler inserts counted vmcnt for st0/wstA here
  DSWRITE_W(0, wstA);
  BARRIER();

#pragma unroll
  for (int k = 0; k < KOFF; ++k) {
    if (k + 1 < KOFF) {          // stage tap k+1 into LDS slot (k+1)&1
      const int s = (k + 1) % 3;
      if (s == 0)      DSWRITE((k + 1) & 1, st0);
      else if (s == 1) DSWRITE((k + 1) & 1, st1);
      else             DSWRITE((k + 1) & 1, st2);
      if ((k + 1) & 1) DSWRITE_W(1, wstB); else DSWRITE_W(0, wstA);
    }
    if (!(k & 1) && k <= 20) GRPLOAD((k + 6) / 2);      // taps k+6, k+7 -> reg
    if ((k & 1) && k <= 21)  RINGWRITE((k + 5) / 2);    // reg -> ring
    if (k + 2 < KOFF) {          // W tap k+2 -> wst[k&1]
      if (k & 1) WGLOAD(k + 2, wstB); else WGLOAD(k + 2, wstA);
    }
    if (k + 3 < KOFF) {          // act tap k+3 -> st[(k+3)%3], row from ring
      int rv = RINGREAD(k + 3);
      const int s = (k + 3) % 3;
      if (s == 0)      GLOAD(st0, rv);
      else if (s == 1) GLOAD(st1, rv);
      else             GLOAD(st2, rv);
    }
    COMPUTE(k & 1);
    if (k + 1 < KOFF) BARRIER();
  }
#undef GRPLOAD
#undef RINGWRITE
#undef RINGREAD
#undef GLOAD
#undef WGLOAD
#undef DSWRITE
#undef DSWRITE_W
#undef COMPUTE
#undef BARRIER

  // D frag: col = cb*32 + r32, row = RH*32 + (r&3) + 8*(r>>2) + 4*half (dtype-independent)
  if (MODE == 0) {
    const int c = cb * 32 + r32;
    float bb = bias[c];
    float s2v = g2[c] * rsqrtf(v2[c] + BN_EPS);
    float o2v = b2[c] - m2[c] * s2v;
#pragma unroll
    for (int r = 0; r < 16; ++r) {
      int rowD = (r & 3) + 8 * (r >> 2) + 4 * half;
      int n = n0 + RH * 32 + rowD;
      if (n < N) {
        int bi = bidx[n];
        float h = acc[r] + bb;
        h = scale_eff[bi * 64 + c] * h + shift[bi * 64 + c];
        float z = h * s2v + o2v;
        out8[(size_t)n * 64 + c] = f2fp8(silu_f(z));
      }
    }
  } else {
    const int c = cb * 32 + r32;
    float bb = bias[c];
#pragma unroll
    for (int r = 0; r < 16; ++r) {
      int rowD = (r & 3) + 8 * (r >> 2) + 4 * half;
      int n = n0 + RH * 32 + rowD;
      if (n < N) {
        out_f[(size_t)n * 64 + c] = acc[r] + bb + xres[(size_t)n * 64 + c];
      }
    }
  }
}

extern "C" void kernel_launch(void* const* d_in, const int* in_sizes, int n_in,
                              void* d_out, int out_size, void* d_ws, size_t ws_size,
                              hipStream_t stream) {
  const float* x    = (const float*)d_in[0];
  const float* t    = (const float*)d_in[1];
  const int*   b    = (const int*)d_in[2];
  const int*   kidx = (const int*)d_in[3];
  const int*   kval = (const int*)d_in[4];
  const float* bn1g = (const float*)d_in[5];
  const float* bn1b = (const float*)d_in[6];
  const float* bn1m = (const float*)d_in[7];
  const float* bn1v = (const float*)d_in[8];
  const float* W1   = (const float*)d_in[9];
  const float* b1c  = (const float*)d_in[10];
  const float* bn2g = (const float*)d_in[11];
  const float* bn2b = (const float*)d_in[12];
  const float* bn2m = (const float*)d_in[13];
  const float* bn2v = (const float*)d_in[14];
  const float* W2   = (const float*)d_in[15];
  const float* b2c  = (const float*)d_in[16];
  const float* Wt   = (const float*)d_in[17];
  const float* bt   = (const float*)d_in[18];
  float* out = (float*)d_out;

  const int N = in_sizes[2];        // 100000
  const int total = N * 64;

  // workspace layout (bytes); act buffers have N+1 rows (row N = zeros), fp8
  char* ws = (char*)d_ws;
  size_t actB = ((size_t)(N + 1) * 64 + 255) & ~(size_t)255;       // 6.4 MB
  unsigned char* a1 = (unsigned char*)ws;
  unsigned char* a2 = (unsigned char*)(ws + actB);
  const size_t wpackB = (size_t)KOFF * 8 * 64 * 8;                 // 110592 B
  unsigned char* W1p = (unsigned char*)(ws + 2 * actB);
  unsigned char* W2p = (unsigned char*)(ws + 2 * actB + wpackB);
  float* scale_eff = (float*)(ws + 2 * actB + 2 * wpackB);
  float* shiftp    = scale_eff + 16 * 64;

  int bnblk = (total / 8 + 8 + 255) / 256;
  prep_all<<<872 + bnblk, 256, 0, stream>>>(t, Wt, bt, scale_eff, shiftp,
                                            W1, W2, W1p, W2p,
                                            x, bn1g, bn1b, bn1m, bn1v, a1, total);

  int nblk = (N + 63) / 64;
  conv_k<0><<<nblk, 256, 0, stream>>>(a1, kidx, kval, W1p, b1c, scale_eff,
                                      shiftp, b, bn2g, bn2b, bn2m, bn2v,
                                      nullptr, a2, nullptr, N);
  conv_k<1><<<nblk, 256, 0, stream>>>(a2, kidx, kval, W2p, b2c, nullptr, nullptr,
                                      nullptr, nullptr, nullptr, nullptr, nullptr,
                                      x, nullptr, out, N);
}